// Round 5
// baseline (148.827 us; speedup 1.0000x reference)
//
#include <hip/hip_runtime.h>

typedef short bf16x8 __attribute__((ext_vector_type(8)));   // 8 bf16 in 4 VGPRs
typedef _Float16 f16x8 __attribute__((ext_vector_type(8))); // 8 f16 in 4 VGPRs
typedef _Float16 f16x2 __attribute__((ext_vector_type(2)));
typedef float f32x4  __attribute__((ext_vector_type(4)));
typedef float f32x2  __attribute__((ext_vector_type(2)));
typedef int   i32x4  __attribute__((ext_vector_type(4)));
typedef unsigned int u32x2 __attribute__((ext_vector_type(2)));

#define DEV static __device__ __forceinline__
#define LOG2E 1.4426950408889634f

DEV float bfu_to_f(unsigned short s) { return __builtin_bit_cast(float, (unsigned int)s << 16); }
DEV unsigned short f_to_bf(float f) {                 // RNE fp32 -> bf16
  unsigned int u = __builtin_bit_cast(unsigned int, f);
  u += 0x7fffu + ((u >> 16) & 1u);
  return (unsigned short)(u >> 16);
}
DEV unsigned int pack_bf_rne(float lo, float hi) {
  return (unsigned int)f_to_bf(lo) | ((unsigned int)f_to_bf(hi) << 16);
}
// packed f32 -> 2x f16 (single v_cvt_pkrtz_f16_f32, full rate)
DEV unsigned int pk_f16(float a, float b) {
  auto h = __builtin_amdgcn_cvt_pkrtz(a, b);
  return __builtin_bit_cast(unsigned int, h);
}
DEV unsigned short f_to_f16(float a) {               // scalar RNE
  return __builtin_bit_cast(unsigned short, (_Float16)a);
}
// guaranteed-native exp2 (single v_exp_f32)
DEV float nexp2(float x) {
#if __has_builtin(__builtin_amdgcn_exp2f)
  return __builtin_amdgcn_exp2f(x);
#else
  return exp2f(x);
#endif
}

// dtype discriminator: adj[0][0] == 1.0 exactly. fp32 word0 == 0x3F800000;
// bf16 word0 low halfword = 0x3F80 != 0 -> never equal.
DEV bool detect_f32(const void* adj) { return ((const float*)adj)[0] == 1.0f; }

template<bool F32> DEV float ldS(const void* p, size_t i) {
  if constexpr (F32) return ((const float*)p)[i];
  else               return bfu_to_f(((const unsigned short*)p)[i]);
}
template<bool F32> DEV void ld8f(const void* p, size_t i, float* o) {
  if constexpr (F32) {
    const float* f = (const float*)p + i;
    f32x4 a = *(const f32x4*)f, b = *(const f32x4*)(f + 4);
    o[0]=a[0]; o[1]=a[1]; o[2]=a[2]; o[3]=a[3];
    o[4]=b[0]; o[5]=b[1]; o[6]=b[2]; o[7]=b[3];
  } else {
    i32x4 w = *(const i32x4*)((const unsigned short*)p + i);
#pragma unroll
    for (int k = 0; k < 4; ++k) {
      unsigned int u = (unsigned int)w[k];
      o[2*k]   = __builtin_bit_cast(float, u << 16);
      o[2*k+1] = __builtin_bit_cast(float, u & 0xffff0000u);
    }
  }
}
template<bool F32> DEV bf16x8 ldfrag(const void* p, size_t i) {
  if constexpr (F32) {
    float o[8]; ld8f<true>(p, i, o);
    union { bf16x8 v; unsigned short u[8]; } r;
#pragma unroll
    for (int k = 0; k < 8; ++k) r.u[k] = f_to_bf(o[k]);
    return r.v;
  } else {
    return __builtin_bit_cast(bf16x8, *(const i32x4*)((const unsigned short*)p + i));
  }
}

// ---------------- Kernel 0: adj -> f16 (handles fp32 or bf16 input) ----------
__global__ __launch_bounds__(256) void k_prep(const void* __restrict__ adj,
                                              unsigned short* __restrict__ adjh) {
  const size_t i0 = ((size_t)blockIdx.x * 256 + threadIdx.x) * 8;   // 4M elems total
  float f[8];
  if (detect_f32(adj)) {
    ld8f<true>(adj, i0, f);
  } else {
    ld8f<false>(adj, i0, f);
  }
  i32x4 o;
#pragma unroll
  for (int k = 0; k < 4; ++k) o[k] = (int)pk_f16(f[2*k], f[2*k+1]);
  *(i32x4*)(adjh + i0) = o;
}

// ---------------- Kernel 1: hT[(b*4+hh)*32+d][n] = (x@W^T) transposed, f16 ----------
template<bool F32> DEV void k_h_body(const void* __restrict__ x, const void* __restrict__ W,
                                     unsigned short* __restrict__ hT,
                                     unsigned short (&t_s)[16][136]) {
  const int tid = threadIdx.x, lane = tid & 63, wave = tid >> 6;
  const int nt = blockIdx.x >> 3, ct = blockIdx.x & 7;    // 128 nt x 8 ct
  const int m = lane & 15, q = lane >> 4;
  bf16x8 wf[4];
#pragma unroll
  for (int k = 0; k < 4; ++k)
    wf[k] = ldfrag<F32>(W, (size_t)(ct * 16 + m) * 128 + q * 8 + k * 32);
#pragma unroll
  for (int s = 0; s < 2; ++s) {
    const int nsub = wave * 2 + s;
    const size_t xr = (size_t)(nt * 128 + nsub * 16 + m) * 128 + q * 8;
    f32x4 acc = {0.f, 0.f, 0.f, 0.f};
#pragma unroll
    for (int k = 0; k < 4; ++k)
      acc = __builtin_amdgcn_mfma_f32_16x16x32_bf16(ldfrag<F32>(x, xr + k * 32), wf[k],
                                                    acc, 0, 0, 0);
    u32x2 w2; w2[0] = pack_bf_rne(acc[0], acc[1]); w2[1] = pack_bf_rne(acc[2], acc[3]);
    *(u32x2*)&t_s[m][nsub * 16 + q * 4] = w2;
  }
  __syncthreads();
  const int row = tid >> 4, c8 = tid & 15;
  const int chg = ct * 16 + row, hh = chg >> 5, dloc = chg & 31;
  const int ng = nt * 128 + c8 * 8, b = ng >> 11, nl = ng & 2047;
  i32x4 v = *(const i32x4*)&t_s[row][c8 * 8];       // 8 bf16
  float f[8];
#pragma unroll
  for (int k = 0; k < 4; ++k) {
    unsigned int u = (unsigned int)v[k];
    f[2*k]   = __builtin_bit_cast(float, u << 16);
    f[2*k+1] = __builtin_bit_cast(float, u & 0xffff0000u);
  }
  i32x4 o;
#pragma unroll
  for (int k = 0; k < 4; ++k) o[k] = (int)pk_f16(f[2*k], f[2*k+1]);
  *(i32x4*)(hT + ((size_t)((b * 4 + hh) * 32 + dloc)) * 2048 + nl) = o;
}
__global__ __launch_bounds__(256) void k_h(const void* x, const void* W,
                                           unsigned short* hT, const void* adj) {
  __shared__ __align__(16) unsigned short t_s[16][136];   // shared across both instantiations
  if (detect_f32(adj)) k_h_body<true>(x, W, hT, t_s); else k_h_body<false>(x, W, hT, t_s);
}

// ---------------- Kernel 1b: src/dst projections -> rank-1 softmax factors ----------
// exp(leaky(s_i+d_j)) = max(exp(s+d), exp(0.2(s+d))); dividing the row by E_i=exp(s_i)
// (cancels in softmax) leaves p'_ij = adj * max(F_j, R_i*H_j) with
// R=exp(-0.8*src), F=exp(dst), H=exp(0.2*dst). All stored as f16 (values O(1);
// f16 is far more precise than the fp8 path this kernel previously passed with).
template<bool F32> DEV void k_sd_body(const unsigned short* __restrict__ hT,
                                      const void* __restrict__ a_src, const void* __restrict__ a_dst,
                                      unsigned int* __restrict__ rvh,
                                      unsigned short* __restrict__ Fh,
                                      unsigned short* __restrict__ Hh) {
  const int t = blockIdx.x * 256 + threadIdx.x;      // (bh, n), n fastest
  const int n = t & 2047, bh = t >> 11, hh = bh & 3;
  const unsigned short* col = hT + (size_t)bh * 32 * 2048 + n;
  float s = 0.f, d = 0.f;
#pragma unroll
  for (int dd = 0; dd < 32; ++dd) {
    const float v = (float)__builtin_bit_cast(_Float16, col[(size_t)dd * 2048]);
    s += v * ldS<F32>(a_src, hh * 32 + dd);
    d += v * ldS<F32>(a_dst, hh * 32 + dd);
  }
  const float R = nexp2(-0.8f * LOG2E * s);          // R_i
  const float F = nexp2(LOG2E * d);                  // F_j
  const float H = nexp2(0.2f * LOG2E * d);           // H_j
  rvh[t] = pk_f16(R, R);                             // broadcast f16 pair
  Fh[t] = f_to_f16(F);
  Hh[t] = f_to_f16(H);
}
__global__ __launch_bounds__(256) void k_sd(const unsigned short* hT, const void* a_src,
                                            const void* a_dst, unsigned int* rvh,
                                            unsigned short* Fh, unsigned short* Hh,
                                            const void* adj) {
  if (detect_f32(adj)) k_sd_body<true>(hT, a_src, a_dst, rvh, Fh, Hh);
  else                 k_sd_body<false>(hT, a_src, a_dst, rvh, Fh, Hh);
}

// ---------------- Kernel 2: all-f16 LDS-staged GAT attention -------------------------
// Rounds 0-4 post-mortem: every structure landed 37-44us at ~9% busy -- the common
// element was 8 fp8 cvt ops per 8j gating each MFMA operand. This version has ZERO
// conversion instructions in the inner loop: adj/V/F/H/R all f16; per 8j per itile:
// v_pk_mul_f16 (R*H) x4, v_pk_max_f16 x4, v_pk_mul_f16 (adj*w) x4 -> feeds
// mfma_f32_16x16x32_f16 directly. Structure = round-4 (best): 32 i-rows/block,
// 128-j chunks, 4 j-quarter waves, double-buffered LDS, reg-prefetch, 1 barrier/chunk.
// Grid = 32 bh x 64 iblk = 2048; LDS 35840 B -> 4 blocks/CU = 16 waves/CU.
struct SmemAttn {
  unsigned char adj[2][32][272];   // 17408 B [buf][i-local][j f16] (256B data + 16 pad)
  unsigned char vt[2][32][272];    // 17408 B [buf][d][j f16]
  unsigned short Fs[2][128];       //   512 B [buf][j]
  unsigned short Hs[2][128];       //   512 B [buf][j]
};                                 // 35840 B

__global__ __launch_bounds__(256, 4) void k_attn(const unsigned short* __restrict__ adjh,
                                                 const unsigned short* __restrict__ hTh,
                                                 const unsigned int* __restrict__ rvh,
                                                 const unsigned short* __restrict__ Fh,
                                                 const unsigned short* __restrict__ Hh,
                                                 unsigned short* __restrict__ ao) {
  __shared__ __align__(16) SmemAttn sm;
  const int tid = threadIdx.x, lane = tid & 63, wave = tid >> 6;   // wave = j-quarter
  const int bh = blockIdx.x & 31, iblk = blockIdx.x >> 5;  // bh-fast: share adj in L2
  const int b = bh >> 2, hh = bh & 3;
  const int m = lane & 15, q = lane >> 4;
  const int i0 = iblk * 32;

  // staging maps (256 threads); all rows are 256 B of f16 data per chunk
  const int ar = tid >> 3, ac = (tid & 7) * 32;      // adj/vt: 32 rows x 8 thr x 32 B
  const bool fstg = tid < 32;                        // F: thr 0-15, H: thr 16-31

  const unsigned char* ap = (const unsigned char*)adjh + (size_t)(i0 + ar) * 4096 + ac;
  const unsigned char* vp = (const unsigned char*)hTh + ((size_t)bh * 32 + ar) * 4096 + ac;
  const unsigned short* fp = (tid < 16 ? Fh : Hh) + (size_t)bh * 2048 + (tid & 15) * 8;

  i32x4 a0r, a1r, v0r, v1r, frr;

  // ---- prologue: stage chunk 0 into buf 0 ----
  a0r = *(const i32x4*)(ap);      a1r = *(const i32x4*)(ap + 16);
  v0r = *(const i32x4*)(vp);      v1r = *(const i32x4*)(vp + 16);
  if (fstg) frr = *(const i32x4*)fp;
  *(i32x4*)&sm.adj[0][ar][ac]      = a0r;
  *(i32x4*)&sm.adj[0][ar][ac + 16] = a1r;
  *(i32x4*)&sm.vt[0][ar][ac]       = v0r;
  *(i32x4*)&sm.vt[0][ar][ac + 16]  = v1r;
  if (fstg) {
    unsigned short* d = (tid < 16) ? &sm.Fs[0][(tid & 15) * 8] : &sm.Hs[0][(tid & 15) * 8];
    *(i32x4*)d = frr;
  }
  __syncthreads();

  unsigned int riw[2];
#pragma unroll
  for (int it = 0; it < 2; ++it)
    riw[it] = rvh[bh * 2048 + i0 + it * 16 + m];

  f32x4 accA[2], accB[2], accD[2];
#pragma unroll
  for (int it = 0; it < 2; ++it) {
    accA[it] = f32x4{0.f,0.f,0.f,0.f};
    accB[it] = f32x4{0.f,0.f,0.f,0.f};
    accD[it] = f32x4{0.f,0.f,0.f,0.f};
  }
  const i32x4 onev = {0x3C003C00, 0x3C003C00, 0x3C003C00, 0x3C003C00};
  const f16x8 ONE8 = __builtin_bit_cast(f16x8, onev);  // 8x f16 1.0

  const int jq = wave * 32 + q * 8;                  // j element base within chunk
  const int jb = jq * 2;                             // byte offset

#pragma unroll 2
  for (int c = 0; c < 16; ++c) {
    const int cb = c & 1;
    if (c < 15) {                                    // issue chunk c+1 loads (coalesced)
      const int o = (c + 1) * 256;                   // bytes
      a0r = *(const i32x4*)(ap + o);      a1r = *(const i32x4*)(ap + o + 16);
      v0r = *(const i32x4*)(vp + o);      v1r = *(const i32x4*)(vp + o + 16);
      if (fstg) frr = *(const i32x4*)(fp + (c + 1) * 128);
    }
    // ---- compute: this wave's 32-j quarter on buf cb (all f16, no conversions) ----
    const f16x8 A0 = *(const f16x8*)&sm.vt[cb][m][jb];        // V^T row d=m
    const f16x8 A1 = *(const f16x8*)&sm.vt[cb][16 + m][jb];   // d=m+16
    const f16x8 F8 = *(const f16x8*)&sm.Fs[cb][jq];
    const f16x8 H8 = *(const f16x8*)&sm.Hs[cb][jq];
#pragma unroll
    for (int it = 0; it < 2; ++it) {
      const f16x8 aw = *(const f16x8*)&sm.adj[cb][it * 16 + m][jb];
      const i32x4 rb = {(int)riw[it], (int)riw[it], (int)riw[it], (int)riw[it]};
      const f16x8 R8 = __builtin_bit_cast(f16x8, rb);
      const f16x8 w8 = __builtin_elementwise_max(F8, R8 * H8); // exp(leaky)/E_i
      const f16x8 p8 = aw * w8;
      accA[it] = __builtin_amdgcn_mfma_f32_16x16x32_f16(A0,   p8, accA[it], 0, 0, 0);
      accB[it] = __builtin_amdgcn_mfma_f32_16x16x32_f16(A1,   p8, accB[it], 0, 0, 0);
      accD[it] = __builtin_amdgcn_mfma_f32_16x16x32_f16(ONE8, p8, accD[it], 0, 0, 0);
    }
    if (c < 15) {                                    // write chunk c+1 into other buffer
      const int nb = cb ^ 1;
      *(i32x4*)&sm.adj[nb][ar][ac]      = a0r;
      *(i32x4*)&sm.adj[nb][ar][ac + 16] = a1r;
      *(i32x4*)&sm.vt[nb][ar][ac]       = v0r;
      *(i32x4*)&sm.vt[nb][ar][ac + 16]  = v1r;
      if (fstg) {
        unsigned short* d = (tid < 16) ? &sm.Fs[nb][(tid & 15) * 8] : &sm.Hs[nb][(tid & 15) * 8];
        *(i32x4*)d = frr;
      }
    }
    __syncthreads();
  }

  // ---- 2-round tree merge of the 4 j-quarter partials (reuse sm as scratch) ----
  // Region = 2 it x 64 lanes x 12 f32 = 1536 f32. Waves 1,3 -> regions 0,1; waves
  // 0,2 add; wave 2 -> region 0; wave 0 adds, finalizes, stores.
  float* red = (float*)&sm;
  if (wave == 1 || wave == 3) {
    const int reg = (wave >> 1) * 1536;
#pragma unroll
    for (int it = 0; it < 2; ++it) {
      const int base = reg + (it * 64 + lane) * 12;
      *(f32x4*)&red[base]     = accA[it];
      *(f32x4*)&red[base + 4] = accB[it];
      red[base + 8] = accD[it][0];
    }
  }
  __syncthreads();
  if (wave == 0 || wave == 2) {
    const int reg = (wave >> 1) * 1536;
#pragma unroll
    for (int it = 0; it < 2; ++it) {
      const int base = reg + (it * 64 + lane) * 12;
      accA[it] += *(const f32x4*)&red[base];
      accB[it] += *(const f32x4*)&red[base + 4];
      accD[it][0] += red[base + 8];
    }
  }
  __syncthreads();
  if (wave == 2) {
#pragma unroll
    for (int it = 0; it < 2; ++it) {
      const int base = (it * 64 + lane) * 12;
      *(f32x4*)&red[base]     = accA[it];
      *(f32x4*)&red[base + 4] = accB[it];
      red[base + 8] = accD[it][0];
    }
  }
  __syncthreads();
  if (wave == 0) {
#pragma unroll
    for (int it = 0; it < 2; ++it) {
      const int base = (it * 64 + lane) * 12;
      const f32x4 a0 = accA[it] + *(const f32x4*)&red[base];
      const f32x4 a1 = accB[it] + *(const f32x4*)&red[base + 4];
      const float den = accD[it][0] + red[base + 8];
      const float inv = 1.f / fmaxf(den, 1e-20f);
      const int il = it * 16 + m;
      // D: col = m = i, row = q*4+r = d. Lane writes channels q*4..+3 and 16+q*4..+3.
      unsigned short* op = ao + ((size_t)(b * 2048) + i0 + il) * 128 + hh * 32 + q * 4;
      u32x2 w0, w1;
      w0[0] = pack_bf_rne(a0[0] * inv, a0[1] * inv);
      w0[1] = pack_bf_rne(a0[2] * inv, a0[3] * inv);
      w1[0] = pack_bf_rne(a1[0] * inv, a1[1] * inv);
      w1[1] = pack_bf_rne(a1[2] * inv, a1[3] * inv);
      *(u32x2*)op        = w0;
      *(u32x2*)(op + 16) = w1;
    }
  }
}

// ---------------- Kernel 3: y = LN(ao @ Wo^T + bo + x) ----------------
template<bool F32> DEV void k_out_body(const unsigned short* __restrict__ ao,
                                       const void* __restrict__ Wo, const void* __restrict__ bo,
                                       const void* __restrict__ x, const void* __restrict__ gamma,
                                       const void* __restrict__ beta, void* __restrict__ out,
                                       float (&y_s)[16][132]) {
  const int tid = threadIdx.x, lane = tid & 63, wave = tid >> 6;
  const int m = lane & 15, q = lane >> 4;
  const int rbase = blockIdx.x * 16;
  bf16x8 af[4];
#pragma unroll
  for (int k = 0; k < 4; ++k)
    af[k] = ldfrag<false>(ao, ((size_t)(rbase + m)) * 128 + q * 8 + k * 32);
  f32x4 acc[2] = {{0.f,0.f,0.f,0.f},{0.f,0.f,0.f,0.f}};
#pragma unroll
  for (int ct = 0; ct < 2; ++ct) {
    const size_t wrow = (size_t)(wave * 32 + ct * 16 + m) * 128 + q * 8;
#pragma unroll
    for (int k = 0; k < 4; ++k)
      acc[ct] = __builtin_amdgcn_mfma_f32_16x16x32_bf16(af[k], ldfrag<F32>(Wo, wrow + k * 32),
                                                        acc[ct], 0, 0, 0);
  }
#pragma unroll
  for (int ct = 0; ct < 2; ++ct) {
    const int c = wave * 32 + ct * 16 + m;
    const float bov = ldS<F32>(bo, c);
#pragma unroll
    for (int r = 0; r < 4; ++r) {
      const int row = q * 4 + r;
      y_s[row][c] = acc[ct][r] + bov + ldS<F32>(x, (size_t)(rbase + row) * 128 + c);
    }
  }
  __syncthreads();
  const int r = tid >> 4, c16 = tid & 15;
  float vals[8], sum = 0.f, sq = 0.f;
#pragma unroll
  for (int k = 0; k < 8; ++k) {
    const float v = y_s[r][c16 * 8 + k];
    vals[k] = v; sum += v; sq += v * v;
  }
#pragma unroll
  for (int msk = 1; msk < 16; msk <<= 1) {
    sum += __shfl_xor(sum, msk, 16);
    sq  += __shfl_xor(sq,  msk, 16);
  }
  const float mu  = sum * (1.f / 128.f);
  const float var = fmaxf(sq * (1.f / 128.f) - mu * mu, 0.f);
  const float rstd = rsqrtf(var + 1e-5f);
  float o[8];
#pragma unroll
  for (int k = 0; k < 8; ++k) {
    const int c = c16 * 8 + k;
    o[k] = (vals[k] - mu) * rstd * ldS<F32>(gamma, c) + ldS<F32>(beta, c);
  }
  const size_t obase = (size_t)(rbase + r) * 128 + c16 * 8;
  if constexpr (F32) {
    float* op = (float*)out + obase;
    f32x4 w0 = {o[0],o[1],o[2],o[3]}, w1 = {o[4],o[5],o[6],o[7]};
    *(f32x4*)op = w0; *(f32x4*)(op + 4) = w1;
  } else {
    union { unsigned short u[8]; i32x4 v; } ob;
#pragma unroll
    for (int k = 0; k < 8; ++k) ob.u[k] = f_to_bf(o[k]);
    *(i32x4*)((unsigned short*)out + obase) = ob.v;
  }
}
__global__ __launch_bounds__(256) void k_out(const unsigned short* ao, const void* Wo,
                                             const void* bo, const void* x, const void* gamma,
                                             const void* beta, void* out, const void* adj) {
  __shared__ __align__(16) float y_s[16][132];   // shared across both instantiations
  if (detect_f32(adj)) k_out_body<true>(ao, Wo, bo, x, gamma, beta, out, y_s);
  else                 k_out_body<false>(ao, Wo, bo, x, gamma, beta, out, y_s);
}

// ---------------- launch ----------------
extern "C" void kernel_launch(void* const* d_in, const int* in_sizes, int n_in,
                              void* d_out, int out_size, void* d_ws, size_t ws_size,
                              hipStream_t stream) {
  const void* x     = d_in[0];
  const void* adj   = d_in[1];
  const void* W     = d_in[2];
  const void* a_src = d_in[3];
  const void* a_dst = d_in[4];
  const void* Wo    = d_in[5];
  const void* bo    = d_in[6];
  const void* gamma = d_in[7];
  const void* beta  = d_in[8];

  char* ws = (char*)d_ws;
  unsigned short* hTh   = (unsigned short*)ws;               // 4,194,304 B  f16 hT (BH*32, N)
  unsigned short* ao_ws = (unsigned short*)(ws + 4194304);   // 4,194,304 B  bf16 attn out
  unsigned int*   rvh   = (unsigned int*)(ws + 8388608);     //   262,144 B  f16 pair (R,R)
  unsigned short* Fh    = (unsigned short*)(ws + 8650752);   //   131,072 B  f16 F
  unsigned short* Hh    = (unsigned short*)(ws + 8781824);   //   131,072 B  f16 H
  unsigned short* adjh  = (unsigned short*)(ws + 8912896);   // 8,388,608 B  f16 adj
                                                             // total 17,301,504 B

  k_prep<<<2048, 256, 0, stream>>>(adj, adjh);
  k_h   <<<1024, 256, 0, stream>>>(x, W, hTh, adj);
  k_sd  <<<256,  256, 0, stream>>>(hTh, a_src, a_dst, rvh, Fh, Hh, adj);
  k_attn<<<2048, 256, 0, stream>>>(adjh, hTh, rvh, Fh, Hh, ao_ws);
  k_out <<<1024, 256, 0, stream>>>(ao_ws, Wo, bo, x, gamma, beta, d_out, adj);
}

// Round 6
// 145.380 us; speedup vs baseline: 1.0237x; 1.0237x over previous
//
#include <hip/hip_runtime.h>

typedef short bf16x8 __attribute__((ext_vector_type(8)));   // 8 bf16 in 4 VGPRs
typedef _Float16 f16x8 __attribute__((ext_vector_type(8))); // 8 f16 in 4 VGPRs
typedef float f32x4  __attribute__((ext_vector_type(4)));
typedef float f32x2  __attribute__((ext_vector_type(2)));
typedef int   i32x4  __attribute__((ext_vector_type(4)));
typedef unsigned int u32x2 __attribute__((ext_vector_type(2)));

#define DEV static __device__ __forceinline__
#define LOG2E 1.4426950408889634f

DEV float bfu_to_f(unsigned short s) { return __builtin_bit_cast(float, (unsigned int)s << 16); }
DEV unsigned short f_to_bf(float f) {                 // RNE fp32 -> bf16
  unsigned int u = __builtin_bit_cast(unsigned int, f);
  u += 0x7fffu + ((u >> 16) & 1u);
  return (unsigned short)(u >> 16);
}
DEV unsigned int pack_bf_rne(float lo, float hi) {
  return (unsigned int)f_to_bf(lo) | ((unsigned int)f_to_bf(hi) << 16);
}
// packed f32 -> 2x f16 (single v_cvt_pkrtz_f16_f32, full rate)
DEV unsigned int pk_f16(float a, float b) {
  auto h = __builtin_amdgcn_cvt_pkrtz(a, b);
  return __builtin_bit_cast(unsigned int, h);
}
DEV unsigned short f_to_f16(float a) { return __builtin_bit_cast(unsigned short, (_Float16)a); }
// guaranteed-native exp2 (single v_exp_f32)
DEV float nexp2(float x) {
#if __has_builtin(__builtin_amdgcn_exp2f)
  return __builtin_amdgcn_exp2f(x);
#else
  return exp2f(x);
#endif
}

// dtype discriminator: adj[0][0] == 1.0 exactly. fp32 word0 == 0x3F800000;
// bf16 word0 low halfword = 0x3F80 != 0 -> never equal.
DEV bool detect_f32(const void* adj) { return ((const float*)adj)[0] == 1.0f; }

template<bool F32> DEV float ldS(const void* p, size_t i) {
  if constexpr (F32) return ((const float*)p)[i];
  else               return bfu_to_f(((const unsigned short*)p)[i]);
}
template<bool F32> DEV void ld8f(const void* p, size_t i, float* o) {
  if constexpr (F32) {
    const float* f = (const float*)p + i;
    f32x4 a = *(const f32x4*)f, b = *(const f32x4*)(f + 4);
    o[0]=a[0]; o[1]=a[1]; o[2]=a[2]; o[3]=a[3];
    o[4]=b[0]; o[5]=b[1]; o[6]=b[2]; o[7]=b[3];
  } else {
    i32x4 w = *(const i32x4*)((const unsigned short*)p + i);
#pragma unroll
    for (int k = 0; k < 4; ++k) {
      unsigned int u = (unsigned int)w[k];
      o[2*k]   = __builtin_bit_cast(float, u << 16);
      o[2*k+1] = __builtin_bit_cast(float, u & 0xffff0000u);
    }
  }
}
template<bool F32> DEV bf16x8 ldfrag(const void* p, size_t i) {
  if constexpr (F32) {
    float o[8]; ld8f<true>(p, i, o);
    union { bf16x8 v; unsigned short u[8]; } r;
#pragma unroll
    for (int k = 0; k < 8; ++k) r.u[k] = f_to_bf(o[k]);
    return r.v;
  } else {
    return __builtin_bit_cast(bf16x8, *(const i32x4*)((const unsigned short*)p + i));
  }
}

// Fragment order for a 16x32 f16 MFMA operand tile: lane l holds elements
// [row = l&15][col = (l>>4)*8 .. +7] at flat offset l*8. One tile = 512 f16 = 1 KB.
// A wave's dwordx4 load at base + lane*16B is perfectly coalesced (1 KB sequential).

// ---------------- Kernel 0: adj -> f16 in fragment-tile order ----------------
// Tile T = it*64 + jt (it: 128 i-tiles, jt: 64 j-tiles). 4 waves/block, 1 tile/wave.
__global__ __launch_bounds__(256) void k_prep(const void* __restrict__ adj,
                                              unsigned short* __restrict__ adjS) {
  const int tid = threadIdx.x, lane = tid & 63, w = tid >> 6;
  const int T = blockIdx.x * 4 + w;                  // 0..8191
  const int it = T >> 6, jt = T & 63;
  const int m = lane & 15, q = lane >> 4;
  const size_t src = (size_t)(it * 16 + m) * 2048 + jt * 32 + q * 8;
  float f[8];
  if (detect_f32(adj)) ld8f<true>(adj, src, f);
  else                 ld8f<false>(adj, src, f);
  i32x4 o;
#pragma unroll
  for (int k = 0; k < 4; ++k) o[k] = (int)pk_f16(f[2*k], f[2*k+1]);
  *(i32x4*)(adjS + (size_t)T * 512 + lane * 8) = o;
}

// ---------------- Kernel 1: vtS = (x@W^T)^T in A-fragment order, f16 ----------------
// vtS tile index: ((bh*2 + dh)*64 + jt); element (d,j): lane = ((j>>3)&3)*16 + (d&15).
template<bool F32> DEV void k_h_body(const void* __restrict__ x, const void* __restrict__ W,
                                     unsigned short* __restrict__ vtS,
                                     unsigned short (&t_s)[16][136]) {
  const int tid = threadIdx.x, lane = tid & 63, wave = tid >> 6;
  const int nt = blockIdx.x >> 3, ct = blockIdx.x & 7;    // 128 nt x 8 ct
  const int m = lane & 15, q = lane >> 4;
  bf16x8 wf[4];
#pragma unroll
  for (int k = 0; k < 4; ++k)
    wf[k] = ldfrag<F32>(W, (size_t)(ct * 16 + m) * 128 + q * 8 + k * 32);
#pragma unroll
  for (int s = 0; s < 2; ++s) {
    const int nsub = wave * 2 + s;
    const size_t xr = (size_t)(nt * 128 + nsub * 16 + m) * 128 + q * 8;
    f32x4 acc = {0.f, 0.f, 0.f, 0.f};
#pragma unroll
    for (int k = 0; k < 4; ++k)
      acc = __builtin_amdgcn_mfma_f32_16x16x32_bf16(ldfrag<F32>(x, xr + k * 32), wf[k],
                                                    acc, 0, 0, 0);
    u32x2 w2; w2[0] = pack_bf_rne(acc[0], acc[1]); w2[1] = pack_bf_rne(acc[2], acc[3]);
    *(u32x2*)&t_s[m][nsub * 16 + q * 4] = w2;
  }
  __syncthreads();
  const int row = tid >> 4, c8 = tid & 15;
  const int chg = ct * 16 + row, hh = chg >> 5, dloc = chg & 31;
  const int ng = nt * 128 + c8 * 8, b = ng >> 11, nl = ng & 2047;
  i32x4 v = *(const i32x4*)&t_s[row][c8 * 8];       // 8 bf16
  float f[8];
#pragma unroll
  for (int k = 0; k < 4; ++k) {
    unsigned int u = (unsigned int)v[k];
    f[2*k]   = __builtin_bit_cast(float, u << 16);
    f[2*k+1] = __builtin_bit_cast(float, u & 0xffff0000u);
  }
  i32x4 o;
#pragma unroll
  for (int k = 0; k < 4; ++k) o[k] = (int)pk_f16(f[2*k], f[2*k+1]);
  const int bh_ = b * 4 + hh;
  const size_t idx = ((size_t)(bh_ * 2 + (dloc >> 4)) * 64 + (nl >> 5)) * 512
                   + (((nl >> 3) & 3) * 16 + (dloc & 15)) * 8;
  *(i32x4*)(vtS + idx) = o;
}
__global__ __launch_bounds__(256) void k_h(const void* x, const void* W,
                                           unsigned short* vtS, const void* adj) {
  __shared__ __align__(16) unsigned short t_s[16][136];   // shared across both instantiations
  if (detect_f32(adj)) k_h_body<true>(x, W, vtS, t_s); else k_h_body<false>(x, W, vtS, t_s);
}

// ---------------- Kernel 1b: src/dst projections -> rank-1 softmax factors ----------
// p'_ij = adj * max(F_j, R_i*H_j), R=exp(-0.8*src), F=exp(dst), H=exp(0.2*dst).
// Reads h from vtS (fragment order) via index math.
template<bool F32> DEV void k_sd_body(const unsigned short* __restrict__ vtS,
                                      const void* __restrict__ a_src, const void* __restrict__ a_dst,
                                      unsigned int* __restrict__ rvh,
                                      unsigned short* __restrict__ Fh,
                                      unsigned short* __restrict__ Hh) {
  const int t = blockIdx.x * 256 + threadIdx.x;      // (bh, n), n fastest
  const int n = t & 2047, bh = t >> 11, hh = bh & 3;
  const unsigned short* colp = vtS + ((size_t)(bh * 2) * 64 + (n >> 5)) * 512
                             + ((n >> 3) & 3) * 128 + (n & 7);
  float s = 0.f, d = 0.f;
#pragma unroll
  for (int dd = 0; dd < 32; ++dd) {
    const float v = (float)__builtin_bit_cast(_Float16,
                      colp[(dd >> 4) * 32768 + (dd & 15) * 8]);
    s += v * ldS<F32>(a_src, hh * 32 + dd);
    d += v * ldS<F32>(a_dst, hh * 32 + dd);
  }
  const float R = nexp2(-0.8f * LOG2E * s);
  const float F = nexp2(LOG2E * d);
  const float H = nexp2(0.2f * LOG2E * d);
  rvh[t] = pk_f16(R, R);                             // broadcast f16 pair
  Fh[t] = f_to_f16(F);
  Hh[t] = f_to_f16(H);
}
__global__ __launch_bounds__(256) void k_sd(const unsigned short* vtS, const void* a_src,
                                            const void* a_dst, unsigned int* rvh,
                                            unsigned short* Fh, unsigned short* Hh,
                                            const void* adj) {
  if (detect_f32(adj)) k_sd_body<true>(vtS, a_src, a_dst, rvh, Fh, Hh);
  else                 k_sd_body<false>(vtS, a_src, a_dst, rvh, Fh, Hh);
}

// ---------------- Kernel 2: zero-LDS streaming GAT attention -------------------------
// r0-r5 invariant: ~1.1 GB of LDS traffic (stage write + frag read) + 16 drain
// barriers/block -> ~38us no matter the wave arrangement. Here operands are
// PRE-SWIZZLED into fragment order, so each wave streams its MFMA operands straight
// from global/L2 with perfectly coalesced sequential dwordx4 loads: NO LDS, NO
// barriers in the main loop. Block = 4 waves = 4 j-quarters of a 32-i-row band;
// each wave: 2 i-tiles x 16 j-tiles; per j-tile: 6 loads, 6 pk-f16 ops, 6 MFMA.
// Grid = 32 bh (fast: 32 consecutive blocks share the same 128KB adjS window in L2)
// x 64 iblk. Epilogue: 2-round LDS tree merge of j-quarter partials (12 KB, 3 barriers).
__global__ __launch_bounds__(256, 4) void k_attn(const unsigned short* __restrict__ adjS,
                                                 const unsigned short* __restrict__ vtS,
                                                 const unsigned int* __restrict__ rvh,
                                                 const unsigned short* __restrict__ Fh,
                                                 const unsigned short* __restrict__ Hh,
                                                 unsigned short* __restrict__ ao) {
  __shared__ __align__(16) float red[3072];          // 12288 B epilogue scratch
  const int tid = threadIdx.x, lane = tid & 63, wave = tid >> 6;   // wave = j-quarter
  const int bh = blockIdx.x & 31, iblk = blockIdx.x >> 5;
  const int b = bh >> 2, hh = bh & 3;
  const int m = lane & 15, q = lane >> 4;
  const int i0 = iblk * 32;
  const int jq0 = wave * 16;                         // first j-tile (of 64) for this wave

  const unsigned short* ap0 = adjS + ((size_t)(iblk * 2    ) * 64 + jq0) * 512 + lane * 8;
  const unsigned short* ap1 = adjS + ((size_t)(iblk * 2 + 1) * 64 + jq0) * 512 + lane * 8;
  const unsigned short* vp0 = vtS + ((size_t)(bh * 2    ) * 64 + jq0) * 512 + lane * 8;
  const unsigned short* vp1 = vtS + ((size_t)(bh * 2 + 1) * 64 + jq0) * 512 + lane * 8;
  const unsigned short* fpF = Fh + (size_t)bh * 2048 + jq0 * 32 + q * 8;
  const unsigned short* fpH = Hh + (size_t)bh * 2048 + jq0 * 32 + q * 8;

  const unsigned int r0 = rvh[bh * 2048 + i0 + m];
  const unsigned int r1 = rvh[bh * 2048 + i0 + 16 + m];
  const i32x4 rb0 = {(int)r0, (int)r0, (int)r0, (int)r0};
  const i32x4 rb1 = {(int)r1, (int)r1, (int)r1, (int)r1};
  const f16x8 R80 = __builtin_bit_cast(f16x8, rb0);
  const f16x8 R81 = __builtin_bit_cast(f16x8, rb1);
  const i32x4 onev = {0x3C003C00, 0x3C003C00, 0x3C003C00, 0x3C003C00};
  const f16x8 ONE8 = __builtin_bit_cast(f16x8, onev);  // 8x f16 1.0

  f32x4 accA[2], accB[2], accD[2];
#pragma unroll
  for (int it = 0; it < 2; ++it) {
    accA[it] = f32x4{0.f,0.f,0.f,0.f};
    accB[it] = f32x4{0.f,0.f,0.f,0.f};
    accD[it] = f32x4{0.f,0.f,0.f,0.f};
  }

#pragma unroll
  for (int j = 0; j < 16; ++j) {
    const i32x4 a0 = *(const i32x4*)(ap0 + j * 512);
    const i32x4 a1 = *(const i32x4*)(ap1 + j * 512);
    const i32x4 v0 = *(const i32x4*)(vp0 + j * 512);
    const i32x4 v1 = *(const i32x4*)(vp1 + j * 512);
    const i32x4 ff = *(const i32x4*)(fpF + j * 32);
    const i32x4 fh = *(const i32x4*)(fpH + j * 32);
    const f16x8 F8 = __builtin_bit_cast(f16x8, ff);
    const f16x8 H8 = __builtin_bit_cast(f16x8, fh);
    const f16x8 A0 = __builtin_bit_cast(f16x8, v0);
    const f16x8 A1 = __builtin_bit_cast(f16x8, v1);
    const f16x8 w0 = __builtin_elementwise_max(F8, R80 * H8);
    const f16x8 p0 = __builtin_bit_cast(f16x8, a0) * w0;
    accA[0] = __builtin_amdgcn_mfma_f32_16x16x32_f16(A0,   p0, accA[0], 0, 0, 0);
    accB[0] = __builtin_amdgcn_mfma_f32_16x16x32_f16(A1,   p0, accB[0], 0, 0, 0);
    accD[0] = __builtin_amdgcn_mfma_f32_16x16x32_f16(ONE8, p0, accD[0], 0, 0, 0);
    const f16x8 w1 = __builtin_elementwise_max(F8, R81 * H8);
    const f16x8 p1 = __builtin_bit_cast(f16x8, a1) * w1;
    accA[1] = __builtin_amdgcn_mfma_f32_16x16x32_f16(A0,   p1, accA[1], 0, 0, 0);
    accB[1] = __builtin_amdgcn_mfma_f32_16x16x32_f16(A1,   p1, accB[1], 0, 0, 0);
    accD[1] = __builtin_amdgcn_mfma_f32_16x16x32_f16(ONE8, p1, accD[1], 0, 0, 0);
  }

  // ---- 2-round tree merge of the 4 j-quarter partials ----
  if (wave == 1 || wave == 3) {
    const int reg = (wave >> 1) * 1536;
#pragma unroll
    for (int it = 0; it < 2; ++it) {
      const int base = reg + (it * 64 + lane) * 12;
      *(f32x4*)&red[base]     = accA[it];
      *(f32x4*)&red[base + 4] = accB[it];
      red[base + 8] = accD[it][0];
    }
  }
  __syncthreads();
  if (wave == 0 || wave == 2) {
    const int reg = (wave >> 1) * 1536;
#pragma unroll
    for (int it = 0; it < 2; ++it) {
      const int base = reg + (it * 64 + lane) * 12;
      accA[it] += *(const f32x4*)&red[base];
      accB[it] += *(const f32x4*)&red[base + 4];
      accD[it][0] += red[base + 8];
    }
  }
  __syncthreads();
  if (wave == 2) {
#pragma unroll
    for (int it = 0; it < 2; ++it) {
      const int base = (it * 64 + lane) * 12;
      *(f32x4*)&red[base]     = accA[it];
      *(f32x4*)&red[base + 4] = accB[it];
      red[base + 8] = accD[it][0];
    }
  }
  __syncthreads();
  if (wave == 0) {
#pragma unroll
    for (int it = 0; it < 2; ++it) {
      const int base = (it * 64 + lane) * 12;
      const f32x4 a0 = accA[it] + *(const f32x4*)&red[base];
      const f32x4 a1 = accB[it] + *(const f32x4*)&red[base + 4];
      const float den = accD[it][0] + red[base + 8];
      const float inv = 1.f / fmaxf(den, 1e-20f);
      const int il = it * 16 + m;
      // D: col = m = i, row = q*4+r = d. Lane writes channels q*4..+3 and 16+q*4..+3.
      unsigned short* op = ao + ((size_t)(b * 2048) + i0 + il) * 128 + hh * 32 + q * 4;
      u32x2 w0, w1;
      w0[0] = pack_bf_rne(a0[0] * inv, a0[1] * inv);
      w0[1] = pack_bf_rne(a0[2] * inv, a0[3] * inv);
      w1[0] = pack_bf_rne(a1[0] * inv, a1[1] * inv);
      w1[1] = pack_bf_rne(a1[2] * inv, a1[3] * inv);
      *(u32x2*)op        = w0;
      *(u32x2*)(op + 16) = w1;
    }
  }
}

// ---------------- Kernel 3: y = LN(ao @ Wo^T + bo + x) ----------------
template<bool F32> DEV void k_out_body(const unsigned short* __restrict__ ao,
                                       const void* __restrict__ Wo, const void* __restrict__ bo,
                                       const void* __restrict__ x, const void* __restrict__ gamma,
                                       const void* __restrict__ beta, void* __restrict__ out,
                                       float (&y_s)[16][132]) {
  const int tid = threadIdx.x, lane = tid & 63, wave = tid >> 6;
  const int m = lane & 15, q = lane >> 4;
  const int rbase = blockIdx.x * 16;
  bf16x8 af[4];
#pragma unroll
  for (int k = 0; k < 4; ++k)
    af[k] = ldfrag<false>(ao, ((size_t)(rbase + m)) * 128 + q * 8 + k * 32);
  f32x4 acc[2] = {{0.f,0.f,0.f,0.f},{0.f,0.f,0.f,0.f}};
#pragma unroll
  for (int ct = 0; ct < 2; ++ct) {
    const size_t wrow = (size_t)(wave * 32 + ct * 16 + m) * 128 + q * 8;
#pragma unroll
    for (int k = 0; k < 4; ++k)
      acc[ct] = __builtin_amdgcn_mfma_f32_16x16x32_bf16(af[k], ldfrag<F32>(Wo, wrow + k * 32),
                                                        acc[ct], 0, 0, 0);
  }
#pragma unroll
  for (int ct = 0; ct < 2; ++ct) {
    const int c = wave * 32 + ct * 16 + m;
    const float bov = ldS<F32>(bo, c);
#pragma unroll
    for (int r = 0; r < 4; ++r) {
      const int row = q * 4 + r;
      y_s[row][c] = acc[ct][r] + bov + ldS<F32>(x, (size_t)(rbase + row) * 128 + c);
    }
  }
  __syncthreads();
  const int r = tid >> 4, c16 = tid & 15;
  float vals[8], sum = 0.f, sq = 0.f;
#pragma unroll
  for (int k = 0; k < 8; ++k) {
    const float v = y_s[r][c16 * 8 + k];
    vals[k] = v; sum += v; sq += v * v;
  }
#pragma unroll
  for (int msk = 1; msk < 16; msk <<= 1) {
    sum += __shfl_xor(sum, msk, 16);
    sq  += __shfl_xor(sq,  msk, 16);
  }
  const float mu  = sum * (1.f / 128.f);
  const float var = fmaxf(sq * (1.f / 128.f) - mu * mu, 0.f);
  const float rstd = rsqrtf(var + 1e-5f);
  float o[8];
#pragma unroll
  for (int k = 0; k < 8; ++k) {
    const int c = c16 * 8 + k;
    o[k] = (vals[k] - mu) * rstd * ldS<F32>(gamma, c) + ldS<F32>(beta, c);
  }
  const size_t obase = (size_t)(rbase + r) * 128 + c16 * 8;
  if constexpr (F32) {
    float* op = (float*)out + obase;
    f32x4 w0 = {o[0],o[1],o[2],o[3]}, w1 = {o[4],o[5],o[6],o[7]};
    *(f32x4*)op = w0; *(f32x4*)(op + 4) = w1;
  } else {
    union { unsigned short u[8]; i32x4 v; } ob;
#pragma unroll
    for (int k = 0; k < 8; ++k) ob.u[k] = f_to_bf(o[k]);
    *(i32x4*)((unsigned short*)out + obase) = ob.v;
  }
}
__global__ __launch_bounds__(256) void k_out(const unsigned short* ao, const void* Wo,
                                             const void* bo, const void* x, const void* gamma,
                                             const void* beta, void* out, const void* adj) {
  __shared__ __align__(16) float y_s[16][132];   // shared across both instantiations
  if (detect_f32(adj)) k_out_body<true>(ao, Wo, bo, x, gamma, beta, out, y_s);
  else                 k_out_body<false>(ao, Wo, bo, x, gamma, beta, out, y_s);
}

// ---------------- launch ----------------
extern "C" void kernel_launch(void* const* d_in, const int* in_sizes, int n_in,
                              void* d_out, int out_size, void* d_ws, size_t ws_size,
                              hipStream_t stream) {
  const void* x     = d_in[0];
  const void* adj   = d_in[1];
  const void* W     = d_in[2];
  const void* a_src = d_in[3];
  const void* a_dst = d_in[4];
  const void* Wo    = d_in[5];
  const void* bo    = d_in[6];
  const void* gamma = d_in[7];
  const void* beta  = d_in[8];

  char* ws = (char*)d_ws;
  unsigned short* adjS  = (unsigned short*)ws;               // 8,388,608 B  f16 adj, frag order
  unsigned short* vtS   = (unsigned short*)(ws + 8388608);   // 4,194,304 B  f16 V^T, frag order
  unsigned short* ao_ws = (unsigned short*)(ws + 12582912);  // 4,194,304 B  bf16 attn out
  unsigned int*   rvh   = (unsigned int*)(ws + 16777216);    //   262,144 B  f16 pair (R,R)
  unsigned short* Fh    = (unsigned short*)(ws + 17039360);  //   131,072 B  f16 F
  unsigned short* Hh    = (unsigned short*)(ws + 17170432);  //   131,072 B  f16 H
                                                             // total 17,301,504 B

  k_prep<<<2048, 256, 0, stream>>>(adj, adjS);
  k_h   <<<1024, 256, 0, stream>>>(x, W, vtS, adj);
  k_sd  <<<256,  256, 0, stream>>>(vtS, a_src, a_dst, rvh, Fh, Hh, adj);
  k_attn<<<2048, 256, 0, stream>>>(adjS, vtS, rvh, Fh, Hh, ao_ws);
  k_out <<<1024, 256, 0, stream>>>(ao_ws, Wo, bo, x, gamma, beta, d_out, adj);
}